// Round 6
// baseline (234.805 us; speedup 1.0000x reference)
//
#include <hip/hip_runtime.h>

// RandomShiftsAug: the reference's grid_sample reduces exactly to an
// integer-pixel shift with replicate clamping:
//   out[n,c,oy,ox] = x[n,c, clamp(oy+sy-pad,0,H-1), clamp(ox+sx-pad,0,W-1)]
// (ix == ox + sx exactly; bilinear weights degenerate to {1,0}).
//
// R6: latency/wave-churn attack. R4 counters showed no busy pipe
// (VALU 11%, hbm 2.5 TB/s, occ 62%) -> one-load-one-store waves are
// round-trip-latency bound. Each thread now handles 4 CONSECUTIVE ROWS
// (same plane, same ox4; 336B stride, shared DRAM pages — unlike R4's
// 28KB plane stride): 4 independent 16B loads issued before any use
// (4x MLP), 4x fewer waves, fixup indices shared across rows.

#define NN 512
#define CC 9
#define HH 84
#define WW 84

typedef float f4u __attribute__((ext_vector_type(4), aligned(4)));   // load, 4B-aligned
typedef float f4a __attribute__((ext_vector_type(4)));               // store, 16B-aligned

__device__ __forceinline__ float sel4(f4u w, int k) {
    return k == 0 ? w.x : (k == 1 ? w.y : (k == 2 ? w.z : w.w));
}

__global__ __launch_bounds__(256) void random_shift_kernel(
    const float* __restrict__ x,
    const int* __restrict__ shift,
    const int* __restrict__ pad_p,
    float* __restrict__ out)
{
    const int pad = pad_p[0];
    const int W4  = WW / 4;                      // 21
    const int HB  = HH / 4;                      // 21 row-groups
    const int total = NN * CC * HB * W4;         // 2,032,128
    int idx = blockIdx.x * blockDim.x + threadIdx.x;
    if (idx >= total) return;

    int ox4 = idx % W4;
    int t   = idx / W4;
    int oyb = t % HB;
    int np  = t / HB;                            // n*CC + c (plane index)
    int n   = np / CC;

    // shift[n,0,0,0] = x-shift (width), shift[n,0,0,1] = y-shift (height)
    int sx = shift[2 * n + 0] - pad;
    int sy = shift[2 * n + 1] - pad;

    int ox = ox4 * 4;
    int s  = ox + sx;                 // window start in source row
    int a  = min(max(s, 0), WW - 4);  // clamped window start (interior: a==s)

    // element j wants src[clamp(s+j,0,W-1)] which lies in [a, a+3]
    int k0 = min(max(s + 0, 0), WW - 1) - a;
    int k1 = min(max(s + 1, 0), WW - 1) - a;
    int k2 = min(max(s + 2, 0), WW - 1) - a;
    int k3 = min(max(s + 3, 0), WW - 1) - a;

    const float* __restrict__ plane_src = x   + (size_t)np * HH * WW;
    float*       __restrict__ plane_dst = out + (size_t)np * HH * WW;

    int oy0 = oyb * 4;
    int sr0 = min(max(oy0 + 0 + sy, 0), HH - 1);
    int sr1 = min(max(oy0 + 1 + sy, 0), HH - 1);
    int sr2 = min(max(oy0 + 2 + sy, 0), HH - 1);
    int sr3 = min(max(oy0 + 3 + sy, 0), HH - 1);

    // 4 independent loads in flight before any use
    f4u w0 = *(const f4u*)(plane_src + sr0 * WW + a);
    f4u w1 = *(const f4u*)(plane_src + sr1 * WW + a);
    f4u w2 = *(const f4u*)(plane_src + sr2 * WW + a);
    f4u w3 = *(const f4u*)(plane_src + sr3 * WW + a);

    f4a v0, v1, v2, v3;
    v0.x = sel4(w0, k0); v0.y = sel4(w0, k1); v0.z = sel4(w0, k2); v0.w = sel4(w0, k3);
    v1.x = sel4(w1, k0); v1.y = sel4(w1, k1); v1.z = sel4(w1, k2); v1.w = sel4(w1, k3);
    v2.x = sel4(w2, k0); v2.y = sel4(w2, k1); v2.z = sel4(w2, k2); v2.w = sel4(w2, k3);
    v3.x = sel4(w3, k0); v3.y = sel4(w3, k1); v3.z = sel4(w3, k2); v3.w = sel4(w3, k3);

    float* d0 = plane_dst + (oy0 + 0) * WW + ox;
    *(f4a*)(d0)            = v0;
    *(f4a*)(d0 + WW)       = v1;
    *(f4a*)(d0 + 2 * WW)   = v2;
    *(f4a*)(d0 + 3 * WW)   = v3;
}

extern "C" void kernel_launch(void* const* d_in, const int* in_sizes, int n_in,
                              void* d_out, int out_size, void* d_ws, size_t ws_size,
                              hipStream_t stream)
{
    const float* x     = (const float*)d_in[0];
    const int*   shift = (const int*)d_in[1];
    const int*   pad   = (const int*)d_in[2];
    float*       out   = (float*)d_out;

    const int total  = NN * CC * (HH / 4) * (WW / 4);
    const int block  = 256;
    const int grid   = (total + block - 1) / block;
    random_shift_kernel<<<grid, block, 0, stream>>>(x, shift, pad, out);
}